// Round 11
// baseline (132.728 us; speedup 1.0000x reference)
//
#include <hip/hip_runtime.h>
#include <hip/hip_bf16.h>
#include <math.h>

// Problem constants
#define B_  4
#define S_  1024
#define D_  512
#define H_  8
#define HD_ 64
#define EPS_ 1e-5f

typedef __attribute__((ext_vector_type(8))) short  bf16x8;
typedef __attribute__((ext_vector_type(4))) float  f32x4;

#define MFMA16(a, b, c) __builtin_amdgcn_mfma_f32_16x16x32_bf16((a), (b), (c), 0, 0, 0)

// async global->LDS DMA, 16B per lane; LDS dest = wave-uniform base + lane*16
#define GLOAD16(gp, lp) __builtin_amdgcn_global_load_lds( \
    (const __attribute__((address_space(1))) unsigned int*)(gp), \
    (__attribute__((address_space(3))) unsigned int*)(lp), 16, 0, 0)

__device__ __forceinline__ float bf2f(short u) {
    union { unsigned int i; float f; } v;
    v.i = ((unsigned int)(unsigned short)u) << 16;
    return v.f;
}
__device__ __forceinline__ short f2bf(float f) {
    __hip_bfloat16 h = __float2bfloat16(f);
    return *reinterpret_cast<short*>(&h);
}

// ---------------------------------------------------------------------------
// Kernel 0: convert x -> bf16, pack [Wq;Wk;Wv;Wg] -> Wcat bf16 (1664x512,
// zero-padded rows 1568..1663), Wo -> bf16, build rope table {cos,sin}.
// ---------------------------------------------------------------------------
__global__ __launch_bounds__(256) void convert_inputs(
    const float* __restrict__ x,
    const float* __restrict__ Wq, const float* __restrict__ Wk,
    const float* __restrict__ Wv, const float* __restrict__ Wg,
    const float* __restrict__ Wo,
    short* __restrict__ xbf, short* __restrict__ Wcat, short* __restrict__ Wobf,
    float2* __restrict__ rope)
{
    const int id = blockIdx.x * 256 + threadIdx.x;   // 0..434175
    if (id < 262144) {                               // x: 2,097,152 elems
        const size_t e = (size_t)id * 8;
        float4 v0 = *(const float4*)(x + e);
        float4 v1 = *(const float4*)(x + e + 4);
        bf16x8 o = { f2bf(v0.x), f2bf(v0.y), f2bf(v0.z), f2bf(v0.w),
                     f2bf(v1.x), f2bf(v1.y), f2bf(v1.z), f2bf(v1.w) };
        *(bf16x8*)(xbf + e) = o;
    } else if (id < 368640) {                        // Wcat: 1664*512 elems
        const int i2 = id - 262144;
        const int row = i2 >> 6;
        const int c8 = (i2 & 63) * 8;
        const float* s = nullptr;
        if (row < 512)       s = Wq + (size_t)row * 512 + c8;
        else if (row < 1024) s = Wk + (size_t)(row - 512) * 512 + c8;
        else if (row < 1536) s = Wv + (size_t)(row - 1024) * 512 + c8;
        else if (row < 1568) s = Wg + (size_t)(row - 1536) * 512 + c8;
        bf16x8 o = (bf16x8)0;
        if (s) {
            float4 v0 = *(const float4*)(s);
            float4 v1 = *(const float4*)(s + 4);
            o = bf16x8{ f2bf(v0.x), f2bf(v0.y), f2bf(v0.z), f2bf(v0.w),
                        f2bf(v1.x), f2bf(v1.y), f2bf(v1.z), f2bf(v1.w) };
        }
        *(bf16x8*)(Wcat + (size_t)row * 512 + c8) = o;
    } else if (id < 401408) {                        // Wo: 262,144 elems
        const int i3 = id - 368640;
        const size_t e = (size_t)i3 * 8;
        float4 v0 = *(const float4*)(Wo + e);
        float4 v1 = *(const float4*)(Wo + e + 4);
        bf16x8 o = { f2bf(v0.x), f2bf(v0.y), f2bf(v0.z), f2bf(v0.w),
                     f2bf(v1.x), f2bf(v1.y), f2bf(v1.z), f2bf(v1.w) };
        *(bf16x8*)(Wobf + e) = o;
    } else {                                         // rope: 32768 entries
        const int i4 = id - 401408;
        const int s = i4 >> 5, i = i4 & 31;
        const float inv = exp2f(-(float)i * (13.287712379549449f / 32.0f));
        float sn, cs;
        sincosf((float)s * inv, &sn, &cs);
        rope[i4] = make_float2(cs, sn);
    }
}

// ---------------------------------------------------------------------------
// Kernel 1: fused per-(b,h,chunk) projection + state delta.
// Block (b,h,c): GEMM x @ [Wq_h|Wk_h|Wv_h|Wg_h]^T (64x208x512) -> LDS;
// RoPE; gates; log2-cumprod; writes roped Qbf/Kbf, Vbf (bf16 coalesced),
// per-token scalars -> SCAL, U_m = V^T@Ksc_m -> Ubuf, R_m -> SRb.
// Consecutive h-blocks of one (b,c) are 16 apart -> same XCD (x L2 reuse).
// ---------------------------------------------------------------------------
__global__ __launch_bounds__(256) void proj_scan_a(
    const short* __restrict__ xbf, const short* __restrict__ Wcat,
    const float2* __restrict__ rope, const float* __restrict__ bg,
    const float* __restrict__ logit_alphas,
    short* __restrict__ Qbf, short* __restrict__ Kbf, short* __restrict__ Vbf,
    short* __restrict__ Ubuf, float* __restrict__ SRb, float* __restrict__ SCAL)
{
    __shared__ __align__(16) char smem[58368];
    short* sQ   = (short*)(smem);            // 64x72 bf16 (9216 B)
    short* sK   = (short*)(smem + 9216);
    short* sVT  = (short*)(smem + 18432);    // VT[e][tau]
    short* sP   = (short*)(smem + 27648);    // V row-major / U staging
    short* sSTb = (short*)(smem + 36864);    // KscT[2] (18432 B); also Astage
    float (*sScal)[6] = (float(*)[6])(smem + 55296);  // 1536 B
    float* sKs  = (float*)(smem + 56832);    // [2][64]
    float* sG   = (float*)(smem + 57344);    // [64][4]
    short* Bstage = sQ;                      // 26624 B (spans sQ,sK,sVT)
    short* Astage = sSTb;                    //  8192 B

    const int tid = threadIdx.x;
    const int wave = tid >> 6, lane = tid & 63;
    const int lrow = lane & 15, lgrp = lane >> 4;
    const int c  = blockIdx.x & 15;
    const int bh = blockIdx.x >> 4;
    const int h = bh & 7, b = bh >> 3;
    const int s0 = c * 64;
    const int row0 = wave * 16;
    const int srl = lane >> 3;               // row within 8-row DMA chunk
    const int scs = (lane & 7) * 8;          // col offset (shorts)

    // ---- Phase A1: projection GEMM (M=64 rows, N=208 cols, K=512) ----
    f32x4 acc[13];
    #pragma unroll
    for (int n = 0; n < 13; ++n) acc[n] = (f32x4)0.f;

    for (int step = 0; step < 8; ++step) {
        const int kt = step * 64;
        #pragma unroll
        for (int i = 0; i < 2; ++i) {        // A: 8 chunks of 8 rows
            const int ch = wave * 2 + i;
            const size_t gr = (size_t)(b * S_ + s0 + ch * 8 + srl) * 512 + kt + scs;
            GLOAD16(xbf + gr, Astage + ch * 512);
        }
        #pragma unroll
        for (int i = 0; i < 7; ++i) {        // B: 26 chunks (Q8,K8,V8,G2)
            const int ch = i * 4 + wave;
            if (ch < 26) {
                int grow;
                if (ch < 8)       grow = h * 64 + ch * 8;
                else if (ch < 16) grow = 512 + h * 64 + (ch - 8) * 8;
                else if (ch < 24) grow = 1024 + h * 64 + (ch - 16) * 8;
                else              grow = 1536 + h * 4 + (ch - 24) * 8;
                GLOAD16(Wcat + (size_t)(grow + srl) * 512 + kt + scs, Bstage + ch * 512);
            }
        }
        __syncthreads();
        #pragma unroll
        for (int kk = 0; kk < 2; ++kk) {
            const int kb = kk * 32 + lgrp * 8;
            bf16x8 a = *(const bf16x8*)&Astage[(row0 + lrow) * 64 + kb];
            #pragma unroll
            for (int n = 0; n < 13; ++n) {
                bf16x8 bb = *(const bf16x8*)&Bstage[(n * 16 + lrow) * 64 + kb];
                acc[n] = MFMA16(a, bb, acc[n]);
            }
        }
        __syncthreads();
    }

    // ---- Phase A2: acc -> LDS (Q,K row-major; V transposed + row-major; G) ----
    #pragma unroll
    for (int n = 0; n < 4; ++n)
        #pragma unroll
        for (int j = 0; j < 4; ++j) {
            const int r = row0 + lgrp * 4 + j;
            sQ[r * 72 + n * 16 + lrow]    = f2bf(acc[n][j]);
            sK[r * 72 + n * 16 + lrow]    = f2bf(acc[4 + n][j]);
            const short vb = f2bf(acc[8 + n][j]);
            sVT[(n * 16 + lrow) * 72 + r] = vb;
            sP [r * 72 + n * 16 + lrow]   = vb;
        }
    if (lrow < 4)
        #pragma unroll
        for (int j = 0; j < 4; ++j)
            sG[(row0 + lgrp * 4 + j) * 4 + lrow] = acc[12][j];
    __syncthreads();

    // gates (tid<64) + RoPE on Q,K in LDS (all threads)
    if (tid < 64) {
        const float g0 = sG[tid * 4 + 0] + bg[h * 4 + 0];
        const float g1 = sG[tid * 4 + 1] + bg[h * 4 + 1];
        const float g2 = sG[tid * 4 + 2] + bg[h * 4 + 2];
        const float g3 = sG[tid * 4 + 3] + bg[h * 4 + 3];
        const float gf  = 1.f / (1.f + expf(-g0));
        const float gu  = 1.f / (1.f + expf(-g1));
        const float wm0 = 1.f / (1.f + expf(-(g2 - g3)));
        const float a0 = 1.f / (1.f + expf(-logit_alphas[h * 2 + 0]));
        const float a1 = 1.f / (1.f + expf(-logit_alphas[h * 2 + 1]));
        sScal[tid][0] = a0 * gf; sScal[tid][1] = a1 * gf;
        sScal[tid][2] = wm0 * gu; sScal[tid][3] = (1.f - wm0) * gu;
        sScal[tid][4] = wm0; sScal[tid][5] = 1.f - wm0;
    }
    #pragma unroll
    for (int it = 0; it < 2; ++it) {
        const int i = tid + it * 256;        // 0..511: (row, 8-col seg)
        const int r = i >> 3, c8 = (i & 7) * 8;
        const int s = s0 + r;
        bf16x8 q8 = *(const bf16x8*)&sQ[r * 72 + c8];
        bf16x8 k8 = *(const bf16x8*)&sK[r * 72 + c8];
        bf16x8 qo, ko;
        #pragma unroll
        for (int j = 0; j < 4; ++j) {
            const float2 t = rope[s * 32 + (c8 >> 1) + j];
            const float qx = bf2f(q8[2 * j]), qy = bf2f(q8[2 * j + 1]);
            const float kx = bf2f(k8[2 * j]), ky = bf2f(k8[2 * j + 1]);
            qo[2 * j]     = f2bf(qx * t.x - qy * t.y);
            qo[2 * j + 1] = f2bf(qx * t.y + qy * t.x);
            ko[2 * j]     = f2bf(kx * t.x - ky * t.y);
            ko[2 * j + 1] = f2bf(kx * t.y + ky * t.x);
        }
        *(bf16x8*)&sQ[r * 72 + c8] = qo;
        *(bf16x8*)&sK[r * 72 + c8] = ko;
    }
    // V global write (row-major copy in sP; stable since A2 barrier)
    #pragma unroll
    for (int it = 0; it < 2; ++it) {
        const int i = tid + it * 256;
        const int r = i >> 3, seg = (i & 7) * 8;
        *(bf16x8*)(Vbf + ((size_t)(b * S_ + s0 + r)) * 512 + h * 64 + seg) =
            *(const bf16x8*)&sP[r * 72 + seg];
    }
    __syncthreads();

    // log2-cumprod; scale vectors; export SCAL + R
    if (wave < 2) {
        const int m = wave;
        float pre = log2f(sScal[lane][m]);
        #pragma unroll
        for (int off = 1; off < 64; off <<= 1) {
            const float u = __shfl_up(pre, off);
            if (lane >= off) pre += u;
        }
        const float lR = __shfl(pre, 63);
        sKs[m * 64 + lane] = sScal[lane][2 + m] * exp2f(lR - pre);
        float* sc = SCAL + ((size_t)(bh * S_) + s0 + lane) * 8;
        sc[0 + m] = pre;
        sc[2 + m] = sScal[lane][2 + m];
        sc[4 + m] = sScal[lane][4 + m];
        sc[6 + m] = sScal[lane][4 + m] * exp2f(pre);
        if (lane == 63) SRb[blockIdx.x * 2 + m] = exp2f(lR);
    }
    // Q/K global writes (roped; final since previous barrier)
    #pragma unroll
    for (int it = 0; it < 2; ++it) {
        const int i = tid + it * 256;
        const int r = i >> 3, seg = (i & 7) * 8;
        const size_t g = ((size_t)(b * S_ + s0 + r)) * 512 + h * 64 + seg;
        *(bf16x8*)(Qbf + g) = *(const bf16x8*)&sQ[r * 72 + seg];
        *(bf16x8*)(Kbf + g) = *(const bf16x8*)&sK[r * 72 + seg];
    }
    __syncthreads();

    {   // scaled-K transpose: KscT[m][d][tau]
        const int task = tid >> 1, halfd = tid & 1;
        const int m = task >> 6, tau = task & 63;
        short* kt_ = sSTb + m * 4608;
        const float ksc = sKs[m * 64 + tau];
        #pragma unroll
        for (int dd = halfd * 32; dd < halfd * 32 + 32; dd += 8) {
            bf16x8 kr = *(const bf16x8*)&sK[tau * 72 + dd];
            #pragma unroll
            for (int j = 0; j < 8; ++j)
                kt_[(dd + j) * 72 + tau] = f2bf(bf2f(kr[j]) * ksc);
        }
    }
    __syncthreads();

    // U_m = V^T @ Ksc_m  -> Ubuf (bf16, staged coalesced via sP)
    #pragma unroll
    for (int m = 0; m < 2; ++m) {
        f32x4 accU[4];
        #pragma unroll
        for (int db = 0; db < 4; ++db) accU[db] = (f32x4)0.f;
        const short* kt_ = sSTb + m * 4608;
        #pragma unroll
        for (int kk = 0; kk < 2; ++kk) {
            const int kb = kk * 32 + lgrp * 8;
            bf16x8 a = *(const bf16x8*)&sVT[(row0 + lrow) * 72 + kb];
            #pragma unroll
            for (int db = 0; db < 4; ++db) {
                bf16x8 bb = *(const bf16x8*)&kt_[(db * 16 + lrow) * 72 + kb];
                accU[db] = MFMA16(a, bb, accU[db]);
            }
        }
        __syncthreads();
        #pragma unroll
        for (int db = 0; db < 4; ++db)
            #pragma unroll
            for (int r = 0; r < 4; ++r) {
                const int e = row0 + lgrp * 4 + r;
                sP[e * 72 + db * 16 + lrow] = f2bf(accU[db][r]);
            }
        __syncthreads();
        short* ub = Ubuf + ((size_t)blockIdx.x * 2 + m) * 4096;
        #pragma unroll
        for (int it = 0; it < 2; ++it) {
            const int i = tid + it * 256;
            const int e = i >> 3, seg = (i & 7) * 8;
            *(bf16x8*)(ub + e * 64 + seg) = *(const bf16x8*)&sP[e * 72 + seg];
        }
    }
}

// ---------------------------------------------------------------------------
// Kernel C: full output with in-register prefix scan.
// O = P@V (intra) + (qs.Q) @ [S0;S1] (inter) -> Obf.
// Per-token scalars from SCAL: {lc0,lc1,ww0,ww1,wm0,wm1,qs0,qs1}.
// ---------------------------------------------------------------------------
__global__ __launch_bounds__(256) void chunk_o(
    const short* __restrict__ Qbf, const short* __restrict__ Kbf,
    const short* __restrict__ Vbf, const float* __restrict__ SCAL,
    const short* __restrict__ Ubuf, const float* __restrict__ SRb,
    short* __restrict__ Obf)
{
    __shared__ __align__(16) short sQ [64 * 72];
    __shared__ __align__(16) short sK [64 * 72];
    __shared__ __align__(16) short sVT[64 * 72];
    __shared__ __align__(16) short sP [64 * 72];
    __shared__ __align__(16) short sST[2][64 * 72];   // prefix state [m][e][d]
    __shared__ float sScal[64][8];

    const int tid  = threadIdx.x;
    const int wave = tid >> 6, lane = tid & 63;
    const int lrow = lane & 15, lgrp = lane >> 4;
    const int c  = blockIdx.x & 15;
    const int bh = blockIdx.x >> 4;
    const int h = bh & 7, b = bh >> 3;
    const int row0 = wave * 16;
    const int s0 = c * 64;

    if (tid < 64) {
        const float* sc = SCAL + ((size_t)(bh * S_) + s0 + tid) * 8;
        *(float4*)&sScal[tid][0] = *(const float4*)sc;
        *(float4*)&sScal[tid][4] = *(const float4*)(sc + 4);
    }

    // ---- in-register exclusive prefix over previous chunks ----
    float sp[4][8];
    #pragma unroll
    for (int g = 0; g < 4; ++g)
        #pragma unroll
        for (int j = 0; j < 8; ++j) sp[g][j] = 0.f;
    for (int cp = 0; cp < c; ++cp) {
        const int bhc = bh * 16 + cp;
        const float R0 = SRb[bhc * 2 + 0];
        const float R1 = SRb[bhc * 2 + 1];
        const short* ub = Ubuf + (size_t)bhc * 8192;
        #pragma unroll
        for (int g = 0; g < 4; ++g) {
            bf16x8 u = *(const bf16x8*)(ub + g * 2048 + tid * 8);
            const float R = (g < 2) ? R0 : R1;
            #pragma unroll
            for (int j = 0; j < 8; ++j) sp[g][j] = fmaf(R, sp[g][j], bf2f(u[j]));
        }
    }
    #pragma unroll
    for (int g = 0; g < 4; ++g) {
        const int i = g * 2048 + tid * 8;
        const int m = i >> 12, e = (i >> 6) & 63, d = i & 63;
        bf16x8 o;
        #pragma unroll
        for (int j = 0; j < 8; ++j) o[j] = f2bf(sp[g][j]);
        *(bf16x8*)&sST[m][e * 72 + d] = o;
    }

    // load Q,K (pre-roped) + V (transposed)
    #pragma unroll
    for (int it = 0; it < 2; ++it) {
        const int i = tid + it * 256;
        const int r = i >> 3, c8 = (i & 7) * 8;
        const size_t g = ((size_t)(b * S_ + s0 + r)) * 512 + h * 64 + c8;
        *(bf16x8*)&sQ[r * 72 + c8] = *(const bf16x8*)(Qbf + g);
        *(bf16x8*)&sK[r * 72 + c8] = *(const bf16x8*)(Kbf + g);
        bf16x8 v8 = *(const bf16x8*)(Vbf + g);
        #pragma unroll
        for (int j = 0; j < 8; ++j) sVT[(c8 + j) * 72 + r] = v8[j];
    }
    __syncthreads();

    // QK^T
    f32x4 accS[4], accO[4];
    #pragma unroll
    for (int cb = 0; cb < 4; ++cb) { accS[cb] = (f32x4)0.f; accO[cb] = (f32x4)0.f; }
    #pragma unroll
    for (int kk = 0; kk < 2; ++kk) {
        const int kb = kk * 32 + lgrp * 8;
        bf16x8 a = *(const bf16x8*)&sQ[(row0 + lrow) * 72 + kb];
        #pragma unroll
        for (int cb = 0; cb < 4; ++cb) {
            bf16x8 bb = *(const bf16x8*)&sK[(cb * 16 + lrow) * 72 + kb];
            accS[cb] = MFMA16(a, bb, accS[cb]);
        }
    }

    // O_inter = (qs-scaled Q) @ [S0;S1]
    #pragma unroll
    for (int kk = 0; kk < 4; ++kk) {
        const int k0 = kk * 32 + lgrp * 8;
        const int m = k0 >> 6, d0 = k0 & 63;
        const float qs = sScal[row0 + lrow][6 + m];
        bf16x8 qr = *(const bf16x8*)&sQ[(row0 + lrow) * 72 + d0];
        bf16x8 a;
        #pragma unroll
        for (int j = 0; j < 8; ++j) a[j] = f2bf(bf2f(qr[j]) * qs);
        #pragma unroll
        for (int cb = 0; cb < 4; ++cb) {
            bf16x8 bb = *(const bf16x8*)&sST[m][(cb * 16 + lrow) * 72 + d0];
            accO[cb] = MFMA16(a, bb, accO[cb]);
        }
    }

    // P build (log-space decay ratios, causal mask, gates)
    #pragma unroll
    for (int r = 0; r < 4; ++r) {
        const int t = row0 + lgrp * 4 + r;
        const float wm0 = sScal[t][4], wm1 = sScal[t][5];
        const float lc0t = sScal[t][0], lc1t = sScal[t][1];
        #pragma unroll
        for (int cb = 0; cb < 4; ++cb) {
            const int tau = cb * 16 + lrow;
            float p = 0.f;
            if (tau <= t) {
                const float c0 = wm0 * sScal[tau][2] * exp2f(lc0t - sScal[tau][0]);
                const float c1 = wm1 * sScal[tau][3] * exp2f(lc1t - sScal[tau][1]);
                p = accS[cb][r] * (c0 + c1);
            }
            sP[t * 72 + tau] = f2bf(p);
        }
    }

    // O_intra = P @ V (wave-local sP rows)
    #pragma unroll
    for (int kk = 0; kk < 2; ++kk) {
        const int kb = kk * 32 + lgrp * 8;
        bf16x8 a = *(const bf16x8*)&sP[(row0 + lrow) * 72 + kb];
        #pragma unroll
        for (int cb = 0; cb < 4; ++cb) {
            bf16x8 bb = *(const bf16x8*)&sVT[(cb * 16 + lrow) * 72 + kb];
            accO[cb] = MFMA16(a, bb, accO[cb]);
        }
    }

    // stage O then coalesced bf16x8 writes
    #pragma unroll
    for (int cb = 0; cb < 4; ++cb)
        #pragma unroll
        for (int r = 0; r < 4; ++r) {
            const int t = row0 + lgrp * 4 + r;
            sP[t * 72 + cb * 16 + lrow] = f2bf(accO[cb][r]);
        }
    __syncthreads();
    #pragma unroll
    for (int it = 0; it < 2; ++it) {
        const int i = tid + it * 256;
        const int t = i >> 3, seg = (i & 7) * 8;
        *(bf16x8*)(Obf + ((size_t)(b * S_ + s0 + t)) * 512 + h * 64 + seg) =
            *(const bf16x8*)&sP[t * 72 + seg];
    }
}

// ---------------------------------------------------------------------------
// Kernel 4: MFMA output GEMM, 128x64 tile, grid 256, dbuf DMA.
// Ybf = Obf @ Wo^T + bo + x  (bf16 output, staged coalesced writes).
// ---------------------------------------------------------------------------
__global__ __launch_bounds__(256) void mfma_out(
    const short* __restrict__ Abf, const short* __restrict__ Wobf,
    const float* __restrict__ bo, const float* __restrict__ xres,
    short* __restrict__ Ybf)
{
    __shared__ __align__(16) short lds[24576];   // 2 bufs x (A 8192 + B 4096)

    const int p = blockIdx.x;              // 0..255
    const int xcd = p & 7, slot = p >> 3;  // 32 slots = 4 m-panels x 8 n
    const int by = xcd + 8 * (slot >> 3);
    const int bx = slot & 7;
    const int n0 = bx * 64, m0 = by * 128;

    const int tid = threadIdx.x;
    const int lane = tid & 63, wave = tid >> 6;
    const int lrow = lane & 15, lgrp = lane >> 4;
    const int wr = wave >> 1, wc = wave & 1;
    const int srl = lane >> 3;
    const int scs = (lane & 7) * 8;

    f32x4 acc[4][2];
    #pragma unroll
    for (int i = 0; i < 4; ++i)
        #pragma unroll
        for (int j = 0; j < 2; ++j) acc[i][j] = (f32x4)0.f;

    #define OUT_STAGE(buf, kt)  {                                             \
        short* dA = lds + (buf) * 12288;                                      \
        short* dB = dA + 8192;                                                \
        _Pragma("unroll")                                                     \
        for (int i = 0; i < 4; ++i) {                                         \
            const int chunk = i * 4 + wave;                                   \
            const int r = chunk * 8 + srl;                                    \
            GLOAD16(Abf + (size_t)(m0 + r) * 512 + (kt) + scs, dA + chunk * 512); \
        }                                                                     \
        _Pragma("unroll")                                                     \
        for (int i = 0; i < 2; ++i) {                                         \
            const int chunk = i * 4 + wave;                                   \
            const int r = chunk * 8 + srl;                                    \
            GLOAD16(Wobf + (size_t)(n0 + r) * 512 + (kt) + scs, dB + chunk * 512); \
        } }

    OUT_STAGE(0, 0);
    __syncthreads();
    int cur = 0;
    for (int step = 0; step < 8; ++step) {
        if (step < 7) OUT_STAGE(cur ^ 1, (step + 1) * 64);
        const short* sA = lds + cur * 12288;
        const short* sB = sA + 8192;
        #pragma unroll
        for (int kk = 0; kk < 2; ++kk) {
            const int kb = kk * 32 + lgrp * 8;
            bf16x8 af[4], bfr[2];
            #pragma unroll
            for (int mi = 0; mi < 4; ++mi)
                af[mi] = *(const bf16x8*)&sA[(wr * 64 + mi * 16 + lrow) * 64 + kb];
            #pragma unroll
            for (int ni = 0; ni < 2; ++ni)
                bfr[ni] = *(const bf16x8*)&sB[(wc * 32 + ni * 16 + lrow) * 64 + kb];
            #pragma unroll
            for (int mi = 0; mi < 4; ++mi)
                #pragma unroll
                for (int ni = 0; ni < 2; ++ni)
                    acc[mi][ni] = MFMA16(af[mi], bfr[ni], acc[mi][ni]);
        }
        __syncthreads();
        cur ^= 1;
    }
    #undef OUT_STAGE

    // stage bf16 tile (128 x 64, stride 80 shorts), then y = acc + bo + x
    short* stg = lds;
    #pragma unroll
    for (int mi = 0; mi < 4; ++mi)
        #pragma unroll
        for (int ni = 0; ni < 2; ++ni)
            #pragma unroll
            for (int j = 0; j < 4; ++j) {
                const int rl = wr * 64 + mi * 16 + lgrp * 4 + j;
                const int cl = wc * 32 + ni * 16 + lrow;
                stg[rl * 80 + cl] = f2bf(acc[mi][ni][j]);
            }
    __syncthreads();
    #pragma unroll
    for (int it = 0; it < 4; ++it) {
        const int u = tid + it * 256;
        const int row = u >> 3, seg = (u & 7) * 8;
        const size_t gbase = (size_t)(m0 + row) * 512 + n0 + seg;
        bf16x8 a = *(const bf16x8*)&stg[row * 80 + seg];
        float4 x0 = *(const float4*)(xres + gbase);
        float4 x1 = *(const float4*)(xres + gbase + 4);
        float4 b0 = *(const float4*)(bo + n0 + seg);
        float4 b1 = *(const float4*)(bo + n0 + seg + 4);
        bf16x8 y;
        y[0] = f2bf(bf2f(a[0]) + b0.x + x0.x);
        y[1] = f2bf(bf2f(a[1]) + b0.y + x0.y);
        y[2] = f2bf(bf2f(a[2]) + b0.z + x0.z);
        y[3] = f2bf(bf2f(a[3]) + b0.w + x0.w);
        y[4] = f2bf(bf2f(a[4]) + b1.x + x1.x);
        y[5] = f2bf(bf2f(a[5]) + b1.y + x1.y);
        y[6] = f2bf(bf2f(a[6]) + b1.z + x1.z);
        y[7] = f2bf(bf2f(a[7]) + b1.w + x1.w);
        *(bf16x8*)(Ybf + gbase) = y;
    }
}

// ---------------------------------------------------------------------------
// Kernel 5: LayerNorm over D=512 (bf16 input, fp32 output).
// ---------------------------------------------------------------------------
__global__ __launch_bounds__(256) void ln_kernel(
    const short* __restrict__ Ybf, const float* __restrict__ ln_w,
    const float* __restrict__ ln_b, float* __restrict__ out)
{
    const int wave = threadIdx.x >> 6;
    const int lane = threadIdx.x & 63;
    const int row = blockIdx.x * 4 + wave;   // 0..4095

    bf16x8 v8 = *(const bf16x8*)(Ybf + (size_t)row * 512 + lane * 8);
    float v[8];
    #pragma unroll
    for (int j = 0; j < 8; ++j) v[j] = bf2f(v8[j]);

    float s = 0.f, sq = 0.f;
    #pragma unroll
    for (int j = 0; j < 8; ++j) { s += v[j]; sq += v[j] * v[j]; }
    #pragma unroll
    for (int off = 32; off; off >>= 1) {
        s  += __shfl_xor(s,  off);
        sq += __shfl_xor(sq, off);
    }
    const float mu  = s * (1.f / 512.f);
    const float var = sq * (1.f / 512.f) - mu * mu;
    const float inv = rsqrtf(var + EPS_);

    float4 w0 = *(const float4*)(ln_w + lane * 8);
    float4 w1 = *(const float4*)(ln_w + lane * 8 + 4);
    float4 b0 = *(const float4*)(ln_b + lane * 8);
    float4 b1 = *(const float4*)(ln_b + lane * 8 + 4);
    float4 o0, o1;
    o0.x = (v[0] - mu) * inv * w0.x + b0.x;
    o0.y = (v[1] - mu) * inv * w0.y + b0.y;
    o0.z = (v[2] - mu) * inv * w0.z + b0.z;
    o0.w = (v[3] - mu) * inv * w0.w + b0.w;
    o1.x = (v[4] - mu) * inv * w1.x + b1.x;
    o1.y = (v[5] - mu) * inv * w1.y + b1.y;
    o1.z = (v[6] - mu) * inv * w1.z + b1.z;
    o1.w = (v[7] - mu) * inv * w1.w + b1.w;
    *(float4*)(out + (size_t)row * 512 + lane * 8)     = o0;
    *(float4*)(out + (size_t)row * 512 + lane * 8 + 4) = o1;
}

// ---------------------------------------------------------------------------
extern "C" void kernel_launch(void* const* d_in, const int* in_sizes, int n_in,
                              void* d_out, int out_size, void* d_ws, size_t ws_size,
                              hipStream_t stream)
{
    const float* x   = (const float*)d_in[0];
    const float* Wq  = (const float*)d_in[1];
    const float* Wk  = (const float*)d_in[2];
    const float* Wv  = (const float*)d_in[3];
    const float* Wo  = (const float*)d_in[4];
    const float* bo  = (const float*)d_in[5];
    const float* Wg  = (const float*)d_in[6];
    const float* bg  = (const float*)d_in[7];
    const float* la  = (const float*)d_in[8];
    const float* lnw = (const float*)d_in[9];
    const float* lnb = (const float*)d_in[10];

    const size_t NQ = (size_t)B_ * S_ * D_;          // 2,097,152
    float* ROPE = (float*)d_ws;                      // 65536 f32 (float2 x 32768)
    float* SRb  = ROPE + 65536;                      // 1024 f32
    float* SCAL = SRb + 1024;                        // 32*1024*8 = 262144 f32
    short* xbf  = (short*)(SCAL + 262144);           // 2,097,152
    short* Wcat = xbf + NQ;                          // 851,968
    short* Wobf = Wcat + (size_t)1664 * 512;         // 262,144
    short* Qbf  = Wobf + (size_t)512 * 512;          // 2,097,152
    short* Kbf  = Qbf + NQ;
    short* Vbf  = Kbf + NQ;
    short* Obf  = Vbf + NQ;
    short* Ybf  = Obf + NQ;
    short* Ubuf = Ybf + NQ;                          // 512*2*4096 = 4,194,304

    // 0) dtype conversion / weight packing / rope table
    convert_inputs<<<1696, 256, 0, stream>>>(x, Wq, Wk, Wv, Wg, Wo, xbf, Wcat, Wobf,
                                             (float2*)ROPE);
    // 1) fused per-(b,h,chunk) projection + state delta
    proj_scan_a<<<512, 256, 0, stream>>>(xbf, Wcat, (const float2*)ROPE, bg, la,
                                         Qbf, Kbf, Vbf, Ubuf, SRb, SCAL);
    // 2) full output (prefix + intra + inter fused)
    chunk_o<<<512, 256, 0, stream>>>(Qbf, Kbf, Vbf, SCAL, Ubuf, SRb, Obf);
    // 3) output projection + residual (MFMA, bf16 Y, grid 256)
    mfma_out<<<256, 256, 0, stream>>>(Obf, Wobf, bo, x, Ybf);
    // 4) layernorm
    ln_kernel<<<1024, 256, 0, stream>>>(Ybf, lnw, lnb, (float*)d_out);
}